// Round 7
// baseline (7750.188 us; speedup 1.0000x reference)
//
#include <hip/hip_runtime.h>
#include <hip/hip_bf16.h>
#include <stdint.h>

// ---------------- problem constants ----------------
#define T_SEQ  2000
#define IN_DIM 13
#define HID    128
#define NB     16           // batch rows per pair
#define NPAIR  32           // 512 / NB ; grid = 2*NPAIR
#define NTHR   512          // 8 waves
#define TC     2            // steps per sync chunk
#define SLOTS  4            // ring slots (R = SLOTS/TC = 2 chunks in flight)

// ---------------- LDS ----------------
// producer: hA[2 parity][16][192 cols bf16] = [h_a | x | 1.0], swizzled
// consumer: hB[2 parity][16][128 cols bf16], swizzled (uses first 8KB)
#define HA_STRIDE 384
#define HA_BUF    (NB * HA_STRIDE)     // 6144
#define HB_STRIDE 256
#define HB_BUF    (NB * HB_STRIDE)     // 4096
#define LDS_BYTES (2 * HA_BUF)         // 12288

// ---------------- workspace layout ----------------
// [0,2048)          prod_flag[pair] @ 64B stride (int, signed: 0xAA poison < 0)
// [4096,6144)       cons_flag[pair] @ 64B stride
// [8192, ...)       ring[pair][SLOTS][16][128] bf16  (4KB/slot, 16KB/pair)
#define WS_RING_OFF 8192

typedef __bf16 bf16x8 __attribute__((ext_vector_type(8)));
typedef float  f32x4  __attribute__((ext_vector_type(4)));

__device__ __forceinline__ uint16_t f2bf(float f) {
    union { float f; uint32_t u; } v; v.f = f;
    return (uint16_t)((v.u + 0x7FFFu + ((v.u >> 16) & 1u)) >> 16);  // RNE
}
__device__ __forceinline__ float bf2f(uint16_t b) {
    union { uint32_t u; float f; } v; v.u = ((uint32_t)b) << 16; return v.f;
}

#define LOG2E  1.44269504088896340736f
#define TLOG2E 2.88539008177792681472f

__device__ __forceinline__ void lds_barrier() {
    asm volatile("s_waitcnt lgkmcnt(0)" ::: "memory");
    __builtin_amdgcn_sched_barrier(0);
    __builtin_amdgcn_s_barrier();
    __builtin_amdgcn_sched_barrier(0);
}
__device__ __forceinline__ void full_barrier() {
    asm volatile("s_waitcnt vmcnt(0) lgkmcnt(0)" ::: "memory");
    __builtin_amdgcn_sched_barrier(0);
    __builtin_amdgcn_s_barrier();
    __builtin_amdgcn_sched_barrier(0);
}
__device__ __forceinline__ int flag_ld_acq(int* p) {
    return __hip_atomic_load(p, __ATOMIC_ACQUIRE, __HIP_MEMORY_SCOPE_AGENT);
}
__device__ __forceinline__ void flag_st_rel(int* p, int v) {
    __hip_atomic_store(p, v, __ATOMIC_RELEASE, __HIP_MEMORY_SCOPE_AGENT);
}

__global__ __launch_bounds__(NTHR, 2)
void lstm2_kernel(const float* __restrict__ x,
                  const float* __restrict__ Wih0, const float* __restrict__ Whh0,
                  const float* __restrict__ bih0, const float* __restrict__ bhh0,
                  const float* __restrict__ Wih1, const float* __restrict__ Whh1,
                  const float* __restrict__ bih1, const float* __restrict__ bhh1,
                  const float* __restrict__ Wfc,  const float* __restrict__ bfc,
                  float* __restrict__ out, unsigned char* __restrict__ ws)
{
    __shared__ alignas(16) unsigned char lds[LDS_BYTES];

    const int tid  = threadIdx.x;
    const int lane = tid & 63;
    const int wv   = tid >> 6;     // wave 0..7
    const int ln   = lane & 15;    // batch col / weight row-in-tile
    const int lhi  = lane >> 4;    // k-group 0..3
    const bool producer = (blockIdx.x < NPAIR);
    const int pair = producer ? blockIdx.x : (blockIdx.x - NPAIR);
    const int bs0  = pair * NB;
    const int sw   = (ln & 7) << 4;

    int* pflag = (int*)(ws + (size_t)pair * 64);
    int* cflag = (int*)(ws + 4096 + (size_t)pair * 64);
    unsigned char* ring = ws + WS_RING_OFF + (size_t)pair * (SLOTS * 4096);

    // zero LDS working region
    for (int i = tid; i < LDS_BYTES/4; i += NTHR) ((uint32_t*)lds)[i] = 0u;
    __syncthreads();

    // shared nonlinearity: 4 units -> packed bf16x4 (7 trans/unit)
    auto nl = [&](f32x4 (&ac)[4], f32x4 &cs) -> uint2 {
        float h[4];
        #pragma unroll
        for (int r = 0; r < 4; ++r) {
            const float ei = __builtin_amdgcn_exp2f(-LOG2E  * ac[0][r]);
            const float ef = __builtin_amdgcn_exp2f(-LOG2E  * ac[1][r]);
            const float eg = __builtin_amdgcn_exp2f( TLOG2E * ac[2][r]);
            const float eo = __builtin_amdgcn_exp2f(-LOG2E  * ac[3][r]);
            const float p1 = 1.0f + ef;
            const float p2 = (1.0f + ei) * (1.0f + eg);
            const float num = fmaf(cs[r], p2, (eg - 1.0f) * p1);
            const float c  = num * __builtin_amdgcn_rcpf(p1 * p2);
            cs[r] = c;
            const float ec = __builtin_amdgcn_exp2f(TLOG2E * c);
            h[r] = (ec - 1.0f) * __builtin_amdgcn_rcpf((1.0f + eo) * (1.0f + ec));
        }
        uint2 u2;
        asm("v_cvt_pk_bf16_f32 %0, %1, %2" : "=v"(u2.x) : "v"(h[0]), "v"(h[1]));
        asm("v_cvt_pk_bf16_f32 %0, %1, %2" : "=v"(u2.y) : "v"(h[2]), "v"(h[3]));
        return u2;
    };

    if (producer) {
        // ================== L0 producer ==================
        // init: 1.0 at col 141 (bias slot), both parities; x(0) into hA parity 1
        if (tid < 2*NB) {
            int p = tid >> 4, n = tid & 15;
            int off = p*HA_BUF + n*HA_STRIDE + (282 ^ ((n & 7) << 4));
            *(uint16_t*)(lds + off) = 0x3F80u;
        }
        if (tid < 256) {
            int b = tid >> 4, i = tid & 15;
            if (i < IN_DIM) {
                float xv = x[((size_t)(bs0 + b) * T_SEQ + 0) * IN_DIM + i];
                int off = HA_BUF + b*HA_STRIDE + ((2*(128 + i)) ^ ((b & 7) << 4));
                *(uint16_t*)(lds + off) = f2bf(xv);
            }
        }
        // weights: Whh0 (4 gate-tiles) + x-augmented [Wih0|b0|0] (K=32 layout) in regs
        bf16x8 wA0[4][4], xw[4];
        #pragma unroll
        for (int g = 0; g < 4; ++g) {
            const int grow = (8*g + wv) * 16 + ln;
            #pragma unroll
            for (int kk = 0; kk < 4; ++kk) {
                const float* s = Whh0 + (size_t)grow * HID + kk*32 + lhi*8;
                #pragma unroll
                for (int j = 0; j < 8; ++j) wA0[g][kk][j] = (__bf16)s[j];
            }
            #pragma unroll
            for (int j = 0; j < 8; ++j) {
                const int c = lhi*8 + j;
                float v = 0.0f;
                if (c < IN_DIM)       v = Wih0[(size_t)grow * IN_DIM + c];
                else if (c == IN_DIM) v = bih0[grow] + bhh0[grow];
                xw[g][j] = (__bf16)v;
            }
        }
        f32x4 cA = {0.f,0.f,0.f,0.f};
        __syncthreads();

        #pragma unroll 2
        for (int t = 0; t < T_SEQ; ++t) {
            const int pr  = t & 1;
            const int haR = (pr ^ 1) * HA_BUF;
            const int haW = pr * HA_BUF;

            if ((t & (TC-1)) == 0) {               // chunk start: back-pressure
                const int k = t / TC;
                if (k >= SLOTS/TC) {
                    while (flag_ld_acq(cflag) < k - (SLOTS/TC) + 1)
                        __builtin_amdgcn_s_sleep(1);
                }
            }

            float xpre = 0.0f;                     // prefetch x(t+1)
            if (tid < 256) {
                const int b = tid >> 4, i = tid & 15;
                if (i < IN_DIM) {
                    int tt = t + 1; if (tt >= T_SEQ) tt = T_SEQ - 1;
                    xpre = x[((size_t)(bs0 + b) * T_SEQ + tt) * IN_DIM + i];
                }
            }

            bf16x8 frA[4];
            const int rb = haR + ln * HA_STRIDE;
            #pragma unroll
            for (int kk = 0; kk < 4; ++kk)
                frA[kk] = *(const bf16x8*)(lds + rb + ((kk*64 + lhi*16) ^ sw));
            const bf16x8 frA4 = *(const bf16x8*)(lds + rb + ((256 + lhi*16) ^ sw));

            f32x4 acc[4];
            #pragma unroll
            for (int g = 0; g < 4; ++g) acc[g] = f32x4{0.f,0.f,0.f,0.f};
            #pragma unroll
            for (int kk = 0; kk < 4; ++kk)
                #pragma unroll
                for (int g = 0; g < 4; ++g)
                    acc[g] = __builtin_amdgcn_mfma_f32_16x16x32_bf16(wA0[g][kk], frA[kk], acc[g], 0, 0, 0);
            #pragma unroll
            for (int g = 0; g < 4; ++g)
                acc[g] = __builtin_amdgcn_mfma_f32_16x16x32_bf16(xw[g], frA4, acc[g], 0, 0, 0);

            const uint2 u2 = nl(acc, cA);
            *(uint2*)(lds + haW + ln * HA_STRIDE + ((32*wv + 8*lhi) ^ sw)) = u2;
            *(uint2*)(ring + (t & (SLOTS-1))*4096 + ln*256 + ((wv<<4) + (lhi<<2))*2) = u2;

            if (tid < 256) {                       // stash x(t+1)
                const int b = tid >> 4, i = tid & 15;
                if (i < IN_DIM) {
                    const int off = haW + b*HA_STRIDE + ((2*(128+i)) ^ ((b & 7) << 4));
                    *(uint16_t*)(lds + off) = f2bf(xpre);
                }
            }

            if ((t & (TC-1)) == TC-1) {            // chunk end: publish
                full_barrier();
                if (tid == 0) flag_st_rel(pflag, t/TC + 1);
            } else {
                lds_barrier();
            }
        }
    } else {
        // ================== L1 consumer ==================
        bf16x8 wI[4][4], wH[4][4];
        f32x4 b1[4];
        #pragma unroll
        for (int g = 0; g < 4; ++g) {
            const int grow = (8*g + wv) * 16 + ln;
            #pragma unroll
            for (int kk = 0; kk < 4; ++kk) {
                const float* si = Wih1 + (size_t)grow * HID + kk*32 + lhi*8;
                const float* sh = Whh1 + (size_t)grow * HID + kk*32 + lhi*8;
                #pragma unroll
                for (int j = 0; j < 8; ++j) { wI[g][kk][j] = (__bf16)si[j]; wH[g][kk][j] = (__bf16)sh[j]; }
            }
            const int g0 = (8*g + wv) * 16 + lhi*4;
            #pragma unroll
            for (int r = 0; r < 4; ++r) b1[g][r] = bih1[g0+r] + bhh1[g0+r];
        }
        f32x4 cB = {0.f,0.f,0.f,0.f};
        __syncthreads();

        #pragma unroll 2
        for (int t = 0; t < T_SEQ; ++t) {
            const int pr  = t & 1;
            const int hbR = pr * HB_BUF;
            const int hbW = (pr ^ 1) * HB_BUF;

            if ((t & (TC-1)) == 0) {               // wait for producer chunk
                const int k = t / TC;
                while (flag_ld_acq(pflag) < k + 1)
                    __builtin_amdgcn_s_sleep(1);
            }

            // h_a(t) fragments straight from the ring (global, L2/L3)
            const unsigned char* rs = ring + (t & (SLOTS-1))*4096 + ln*256 + lhi*16;
            bf16x8 gA[4];
            #pragma unroll
            for (int kk = 0; kk < 4; ++kk)
                gA[kk] = *(const bf16x8*)(rs + kk*64);

            bf16x8 frB[4];
            const int rb = hbR + ln * HB_STRIDE;
            #pragma unroll
            for (int kk = 0; kk < 4; ++kk)
                frB[kk] = *(const bf16x8*)(lds + rb + ((kk*64 + lhi*16) ^ sw));

            f32x4 acc[4];
            #pragma unroll
            for (int g = 0; g < 4; ++g) acc[g] = b1[g];
            #pragma unroll
            for (int kk = 0; kk < 4; ++kk)         // Whh1 (LDS) first: covers gA latency
                #pragma unroll
                for (int g = 0; g < 4; ++g)
                    acc[g] = __builtin_amdgcn_mfma_f32_16x16x32_bf16(wH[g][kk], frB[kk], acc[g], 0, 0, 0);
            #pragma unroll
            for (int kk = 0; kk < 4; ++kk)
                #pragma unroll
                for (int g = 0; g < 4; ++g)
                    acc[g] = __builtin_amdgcn_mfma_f32_16x16x32_bf16(wI[g][kk], gA[kk], acc[g], 0, 0, 0);

            const uint2 u2 = nl(acc, cB);
            *(uint2*)(lds + hbW + ln * HB_STRIDE + ((32*wv + 8*lhi) ^ sw)) = u2;

            lds_barrier();
            if ((t & (TC-1)) == TC-1) {            // chunk consumed
                if (tid == 0) flag_st_rel(cflag, t/TC + 1);
            }
        }

        // epilogue: out = h_b(T-1) @ Wfc^T + bfc ; h_b(1999) is in hB parity 0
        if (tid < 64) {
            const int b = tid >> 2, c = tid & 3;
            float s = bfc[c];
            const float* wf = Wfc + (size_t)c * HID;
            const int rowoff = b * HB_STRIDE;
            const int swb = (b & 7) << 4;
            #pragma unroll 8
            for (int k = 0; k < HID; ++k) {
                const uint16_t hb = *(const uint16_t*)(lds + rowoff + ((2*k) ^ swb));
                s += bf2f(hb) * wf[k];
            }
            out[(size_t)(bs0 + b) * 4 + c] = s;
        }
    }
}

extern "C" void kernel_launch(void* const* d_in, const int* in_sizes, int n_in,
                              void* d_out, int out_size, void* d_ws, size_t ws_size,
                              hipStream_t stream) {
    const float* x    = (const float*)d_in[0];
    const float* Wih0 = (const float*)d_in[1];
    const float* Whh0 = (const float*)d_in[2];
    const float* bih0 = (const float*)d_in[3];
    const float* bhh0 = (const float*)d_in[4];
    const float* Wih1 = (const float*)d_in[5];
    const float* Whh1 = (const float*)d_in[6];
    const float* bih1 = (const float*)d_in[7];
    const float* bhh1 = (const float*)d_in[8];
    const float* Wfc  = (const float*)d_in[9];
    const float* bfc  = (const float*)d_in[10];
    (void)in_sizes; (void)n_in; (void)ws_size; (void)out_size;

    hipLaunchKernelGGL(lstm2_kernel, dim3(2*NPAIR), dim3(NTHR), 0, stream,
                       x, Wih0, Whh0, bih0, bhh0, Wih1, Whh1, bih1, bhh1, Wfc, bfc,
                       (float*)d_out, (unsigned char*)d_ws);
}

// Round 8
// 2142.293 us; speedup vs baseline: 3.6177x; 3.6177x over previous
//
#include <hip/hip_runtime.h>
#include <hip/hip_bf16.h>
#include <stdint.h>

// ---------------- problem constants ----------------
#define T_SEQ  2000
#define IN_DIM 13
#define HID    128
#define NB     16           // batch rows per pair
#define NPAIR  32           // grid = 2*NPAIR (producer L0 blocks + consumer L1 blocks)
#define NTHR   512          // 8 waves

// ---------------- LDS ----------------
#define HA_STRIDE 384
#define HA_BUF    (NB * HA_STRIDE)     // 6144
#define HB_STRIDE 256
#define HB_BUF    (NB * HB_STRIDE)     // 4096
#define LDS_BYTES (2 * HA_BUF)         // 12288 (consumer uses first 8KB)

// ---------------- workspace ----------------
// [0,2048)    prod_flag[pair] @64B   (0xAA poison reads as negative int = "0")
// [4096,6144) cons_flag[pair] @64B
// [8192,...)  ring[pair][slots][16][128] bf16 (4KB/slot)
#define WS_RING_OFF 8192

typedef __bf16 bf16x8 __attribute__((ext_vector_type(8)));
typedef float  f32x4  __attribute__((ext_vector_type(4)));

__device__ __forceinline__ uint16_t f2bf(float f) {
    union { float f; uint32_t u; } v; v.f = f;
    return (uint16_t)((v.u + 0x7FFFu + ((v.u >> 16) & 1u)) >> 16);  // RNE
}
__device__ __forceinline__ float bf2f(uint16_t b) {
    union { uint32_t u; float f; } v; v.u = ((uint32_t)b) << 16; return v.f;
}

#define LOG2E  1.44269504088896340736f
#define TLOG2E 2.88539008177792681472f

__device__ __forceinline__ void lds_barrier() {
    asm volatile("s_waitcnt lgkmcnt(0)" ::: "memory");
    __builtin_amdgcn_sched_barrier(0);
    __builtin_amdgcn_s_barrier();
    __builtin_amdgcn_sched_barrier(0);
}
__device__ __forceinline__ void full_barrier() {
    asm volatile("s_waitcnt vmcnt(0) lgkmcnt(0)" ::: "memory");
    __builtin_amdgcn_sched_barrier(0);
    __builtin_amdgcn_s_barrier();
    __builtin_amdgcn_sched_barrier(0);
}
__device__ __forceinline__ void flag_st_rel(int* p, int v) {
    __hip_atomic_store(p, v, __ATOMIC_RELEASE, __HIP_MEMORY_SCOPE_AGENT);
}
// relaxed spin (no per-poll L2 invalidate), one acquire on exit
__device__ __forceinline__ void poll_ge(int* p, int v) {
    int x = __hip_atomic_load(p, __ATOMIC_RELAXED, __HIP_MEMORY_SCOPE_AGENT);
    while (x < v) {
        __builtin_amdgcn_s_sleep(2);
        x = __hip_atomic_load(p, __ATOMIC_RELAXED, __HIP_MEMORY_SCOPE_AGENT);
    }
    (void)__hip_atomic_load(p, __ATOMIC_ACQUIRE, __HIP_MEMORY_SCOPE_AGENT);
}

__global__ __launch_bounds__(NTHR, 2)
void lstm2_kernel(const float* __restrict__ x,
                  const float* __restrict__ Wih0, const float* __restrict__ Whh0,
                  const float* __restrict__ bih0, const float* __restrict__ bhh0,
                  const float* __restrict__ Wih1, const float* __restrict__ Whh1,
                  const float* __restrict__ bih1, const float* __restrict__ bhh1,
                  const float* __restrict__ Wfc,  const float* __restrict__ bfc,
                  float* __restrict__ out, unsigned char* __restrict__ ws,
                  int tcshift, int tcmask, int slotmask, int bp)
{
    __shared__ alignas(16) unsigned char lds[LDS_BYTES];

    const int tid  = threadIdx.x;
    const int lane = tid & 63;
    const int wv   = tid >> 6;     // wave 0..7
    const int ln   = lane & 15;    // batch col / weight row-in-tile
    const int lhi  = lane >> 4;    // k-group 0..3
    const bool producer = (blockIdx.x < NPAIR);
    const int pair = producer ? blockIdx.x : (blockIdx.x - NPAIR);
    const int bs0  = pair * NB;
    const int sw   = (ln & 7) << 4;

    int* pflag = (int*)(ws + (size_t)pair * 64);
    int* cflag = (int*)(ws + 4096 + (size_t)pair * 64);
    unsigned char* ring = ws + WS_RING_OFF + (size_t)pair * ((size_t)(slotmask + 1) * 4096);

    for (int i = tid; i < LDS_BYTES/4; i += NTHR) ((uint32_t*)lds)[i] = 0u;
    __syncthreads();

    // nonlinearity: 4 units -> packed bf16x4 (7 trans/unit)
    auto nl = [&](f32x4 (&ac)[4], f32x4 &cs) -> uint2 {
        float h[4];
        #pragma unroll
        for (int r = 0; r < 4; ++r) {
            const float ei = __builtin_amdgcn_exp2f(-LOG2E  * ac[0][r]);
            const float ef = __builtin_amdgcn_exp2f(-LOG2E  * ac[1][r]);
            const float eg = __builtin_amdgcn_exp2f( TLOG2E * ac[2][r]);
            const float eo = __builtin_amdgcn_exp2f(-LOG2E  * ac[3][r]);
            const float p1 = 1.0f + ef;
            const float p2 = (1.0f + ei) * (1.0f + eg);
            const float num = fmaf(cs[r], p2, (eg - 1.0f) * p1);
            const float c  = num * __builtin_amdgcn_rcpf(p1 * p2);
            cs[r] = c;
            const float ec = __builtin_amdgcn_exp2f(TLOG2E * c);
            h[r] = (ec - 1.0f) * __builtin_amdgcn_rcpf((1.0f + eo) * (1.0f + ec));
        }
        uint2 u2;
        asm("v_cvt_pk_bf16_f32 %0, %1, %2" : "=v"(u2.x) : "v"(h[0]), "v"(h[1]));
        asm("v_cvt_pk_bf16_f32 %0, %1, %2" : "=v"(u2.y) : "v"(h[2]), "v"(h[3]));
        return u2;
    };

    if (producer) {
        // ================== L0 producer ==================
        if (tid < 2*NB) {      // 1.0 at col 141 (bias slot), both parities
            int p = tid >> 4, n = tid & 15;
            int off = p*HA_BUF + n*HA_STRIDE + (282 ^ ((n & 7) << 4));
            *(uint16_t*)(lds + off) = 0x3F80u;
        }
        if (tid < 256) {       // x(0) into hA parity 1
            int b = tid >> 4, i = tid & 15;
            if (i < IN_DIM) {
                float xv = x[((size_t)(bs0 + b) * T_SEQ + 0) * IN_DIM + i];
                int off = HA_BUF + b*HA_STRIDE + ((2*(128 + i)) ^ ((b & 7) << 4));
                *(uint16_t*)(lds + off) = f2bf(xv);
            }
        }
        bf16x8 wA0[4][4], xw[4];
        #pragma unroll
        for (int g = 0; g < 4; ++g) {
            const int grow = (8*g + wv) * 16 + ln;
            #pragma unroll
            for (int kk = 0; kk < 4; ++kk) {
                const float* s = Whh0 + (size_t)grow * HID + kk*32 + lhi*8;
                #pragma unroll
                for (int j = 0; j < 8; ++j) wA0[g][kk][j] = (__bf16)s[j];
            }
            #pragma unroll
            for (int j = 0; j < 8; ++j) {
                const int c = lhi*8 + j;
                float v = 0.0f;
                if (c < IN_DIM)       v = Wih0[(size_t)grow * IN_DIM + c];
                else if (c == IN_DIM) v = bih0[grow] + bhh0[grow];
                xw[g][j] = (__bf16)v;
            }
        }
        f32x4 cA = {0.f,0.f,0.f,0.f};
        __syncthreads();

        #pragma unroll 2
        for (int t = 0; t < T_SEQ; ++t) {
            const int pr  = t & 1;
            const int haR = (pr ^ 1) * HA_BUF;
            const int haW = pr * HA_BUF;

            if ((t & tcmask) == 0) {               // chunk start: back-pressure
                const int k = t >> tcshift;
                if (k >= bp) poll_ge(cflag, k - bp + 1);
            }

            float xpre = 0.0f;                     // prefetch x(t+1)
            if (tid < 256) {
                const int b = tid >> 4, i = tid & 15;
                if (i < IN_DIM) {
                    int tt = t + 1; if (tt >= T_SEQ) tt = T_SEQ - 1;
                    xpre = x[((size_t)(bs0 + b) * T_SEQ + tt) * IN_DIM + i];
                }
            }

            bf16x8 frA[4];
            const int rb = haR + ln * HA_STRIDE;
            #pragma unroll
            for (int kk = 0; kk < 4; ++kk)
                frA[kk] = *(const bf16x8*)(lds + rb + ((kk*64 + lhi*16) ^ sw));
            const bf16x8 frA4 = *(const bf16x8*)(lds + rb + ((256 + lhi*16) ^ sw));

            f32x4 acc[4];
            #pragma unroll
            for (int g = 0; g < 4; ++g) acc[g] = f32x4{0.f,0.f,0.f,0.f};
            #pragma unroll
            for (int kk = 0; kk < 4; ++kk)
                #pragma unroll
                for (int g = 0; g < 4; ++g)
                    acc[g] = __builtin_amdgcn_mfma_f32_16x16x32_bf16(wA0[g][kk], frA[kk], acc[g], 0, 0, 0);
            #pragma unroll
            for (int g = 0; g < 4; ++g)
                acc[g] = __builtin_amdgcn_mfma_f32_16x16x32_bf16(xw[g], frA4, acc[g], 0, 0, 0);

            const uint2 u2 = nl(acc, cA);
            *(uint2*)(lds + haW + ln * HA_STRIDE + ((32*wv + 8*lhi) ^ sw)) = u2;
            *(uint2*)(ring + (size_t)(t & slotmask)*4096 + ln*256 + wv*32 + lhi*8) = u2;

            if (tid < 256) {                       // stash x(t+1)
                const int b = tid >> 4, i = tid & 15;
                if (i < IN_DIM) {
                    const int off = haW + b*HA_STRIDE + ((2*(128+i)) ^ ((b & 7) << 4));
                    *(uint16_t*)(lds + off) = f2bf(xpre);
                }
            }

            if ((t & tcmask) == tcmask || t == T_SEQ-1) {   // publish chunk
                full_barrier();
                if (tid == 0) flag_st_rel(pflag, (t >> tcshift) + 1);
            } else {
                lds_barrier();
            }
        }
    } else {
        // ================== L1 consumer ==================
        bf16x8 wI[4][4], wH[4][4];
        f32x4 b1[4];
        #pragma unroll
        for (int g = 0; g < 4; ++g) {
            const int grow = (8*g + wv) * 16 + ln;
            #pragma unroll
            for (int kk = 0; kk < 4; ++kk) {
                const float* si = Wih1 + (size_t)grow * HID + kk*32 + lhi*8;
                const float* sh = Whh1 + (size_t)grow * HID + kk*32 + lhi*8;
                #pragma unroll
                for (int j = 0; j < 8; ++j) { wI[g][kk][j] = (__bf16)si[j]; wH[g][kk][j] = (__bf16)sh[j]; }
            }
            const int g0 = (8*g + wv) * 16 + lhi*4;
            #pragma unroll
            for (int r = 0; r < 4; ++r) b1[g][r] = bih1[g0+r] + bhh1[g0+r];
        }
        f32x4 cB = {0.f,0.f,0.f,0.f};
        bf16x8 gA[4];
        const int roff = ln*256 + lhi*16;
        auto ldgA = [&](int t) {
            const unsigned char* rs = ring + (size_t)(t & slotmask)*4096 + roff;
            #pragma unroll
            for (int kk = 0; kk < 4; ++kk)
                gA[kk] = *(const bf16x8*)(rs + kk*64);
        };
        __syncthreads();

        #pragma unroll 2
        for (int t = 0; t < T_SEQ; ++t) {
            const int pr  = t & 1;
            const int hbR = pr * HB_BUF;
            const int hbW = (pr ^ 1) * HB_BUF;

            if ((t & tcmask) == 0) {               // wait for producer chunk
                poll_ge(pflag, (t >> tcshift) + 1);
                ldgA(t);                           // exposed once per chunk
            }

            bf16x8 frB[4];
            const int rb = hbR + ln * HB_STRIDE;
            #pragma unroll
            for (int kk = 0; kk < 4; ++kk)
                frB[kk] = *(const bf16x8*)(lds + rb + ((kk*64 + lhi*16) ^ sw));

            f32x4 acc[4];
            #pragma unroll
            for (int g = 0; g < 4; ++g) acc[g] = b1[g];
            #pragma unroll
            for (int kk = 0; kk < 4; ++kk)         // Whh1 (LDS) first: covers gA latency
                #pragma unroll
                for (int g = 0; g < 4; ++g)
                    acc[g] = __builtin_amdgcn_mfma_f32_16x16x32_bf16(wH[g][kk], frB[kk], acc[g], 0, 0, 0);
            #pragma unroll
            for (int kk = 0; kk < 4; ++kk)
                #pragma unroll
                for (int g = 0; g < 4; ++g)
                    acc[g] = __builtin_amdgcn_mfma_f32_16x16x32_bf16(wI[g][kk], gA[kk], acc[g], 0, 0, 0);

            if (((t+1) & tcmask) != 0 && t+1 < T_SEQ)   // in-chunk prefetch of gA(t+1):
                ldgA(t+1);                              // latency hides under nl+barrier+wH

            const uint2 u2 = nl(acc, cB);
            *(uint2*)(lds + hbW + ln * HB_STRIDE + ((32*wv + 8*lhi) ^ sw)) = u2;

            lds_barrier();
            if ((t & tcmask) == tcmask || t == T_SEQ-1) {
                if (tid == 0) flag_st_rel(cflag, (t >> tcshift) + 1);
            }
        }

        // epilogue: out = h_b(T-1) @ Wfc^T + bfc ; h_b(1999) in hB parity 0
        if (tid < 64) {
            const int b = tid >> 2, c = tid & 3;
            float s = bfc[c];
            const float* wf = Wfc + (size_t)c * HID;
            const int rowoff = b * HB_STRIDE;
            const int swb = (b & 7) << 4;
            #pragma unroll 8
            for (int k = 0; k < HID; ++k) {
                const uint16_t hb = *(const uint16_t*)(lds + rowoff + ((2*k) ^ swb));
                s += bf2f(hb) * wf[k];
            }
            out[(size_t)(bs0 + b) * 4 + c] = s;
        }
    }
}

extern "C" void kernel_launch(void* const* d_in, const int* in_sizes, int n_in,
                              void* d_out, int out_size, void* d_ws, size_t ws_size,
                              hipStream_t stream) {
    const float* x    = (const float*)d_in[0];
    const float* Wih0 = (const float*)d_in[1];
    const float* Whh0 = (const float*)d_in[2];
    const float* bih0 = (const float*)d_in[3];
    const float* bhh0 = (const float*)d_in[4];
    const float* Wih1 = (const float*)d_in[5];
    const float* Whh1 = (const float*)d_in[6];
    const float* bih1 = (const float*)d_in[7];
    const float* bhh1 = (const float*)d_in[8];
    const float* Wfc  = (const float*)d_in[9];
    const float* bfc  = (const float*)d_in[10];
    (void)in_sizes; (void)n_in; (void)out_size;

    // size the ring from ws: slots/pair = pow2 in [2,256]; 4KB per slot
    size_t per = (ws_size > WS_RING_OFF)
               ? (ws_size - WS_RING_OFF) / ((size_t)NPAIR * 4096) : 2;
    if (per > 256) per = 256;
    int slots = 2;
    while ((size_t)(slots * 2) <= per && slots < 256) slots *= 2;
    int bp = (slots >= 8) ? 4 : 2;       // chunks in flight
    int tc = slots / bp;                 // steps per chunk (pow2)
    int tcshift = __builtin_ctz(tc);

    hipLaunchKernelGGL(lstm2_kernel, dim3(2*NPAIR), dim3(NTHR), 0, stream,
                       x, Wih0, Whh0, bih0, bhh0, Wih1, Whh1, bih1, bhh1, Wfc, bfc,
                       (float*)d_out, (unsigned char*)d_ws,
                       tcshift, tc - 1, slots - 1, bp);
}